// Round 1
// baseline (710.639 us; speedup 1.0000x reference)
//
#include <hip/hip_runtime.h>
#include <hip/hip_bf16.h>

#define NNODE 50000
#define DIM   256
#define EDGES 400000
#define NET   4
#define NTOT  (NET * NNODE)     // 200000

typedef __attribute__((ext_vector_type(8))) __bf16 bf16x8;
typedef __attribute__((ext_vector_type(4))) float f32x4;
typedef __attribute__((ext_vector_type(4))) unsigned short u16x4;

__device__ __forceinline__ float bf2f(unsigned short u) {
  unsigned int x = ((unsigned int)u) << 16;
  return __builtin_bit_cast(float, x);
}
__device__ __forceinline__ unsigned short f2bf(float f) {
  __hip_bfloat16 h = __float2bfloat16(f);   // RTNE
  return __builtin_bit_cast(unsigned short, h);
}

__global__ void conv_f32_bf16(const float* __restrict__ in, unsigned short* __restrict__ out, int n4) {
  int i = blockIdx.x * blockDim.x + threadIdx.x;
  if (i >= n4) return;
  f32x4 v = reinterpret_cast<const f32x4*>(in)[i];
  u16x4 o;
  o[0] = f2bf(v[0]); o[1] = f2bf(v[1]); o[2] = f2bf(v[2]); o[3] = f2bf(v[3]);
  reinterpret_cast<u16x4*>(out)[i] = o;
}

__global__ void zero_i32(int* __restrict__ p, int n) {
  int i = blockIdx.x * blockDim.x + threadIdx.x;
  if (i < n) p[i] = 0;
}

__global__ void fill_f32(float* __restrict__ p, float v, int n) {
  int i = blockIdx.x * blockDim.x + threadIdx.x;
  if (i < n) p[i] = v;
}

__global__ void count_edges(const int* __restrict__ d0, const int* __restrict__ d1,
                            const int* __restrict__ d2, const int* __restrict__ d3,
                            int* __restrict__ cnt) {
  int t = blockIdx.y;
  const int* dp = (t == 0) ? d0 : (t == 1) ? d1 : (t == 2) ? d2 : d3;
  int i = blockIdx.x * blockDim.x + threadIdx.x;
  if (i < EDGES) atomicAdd(&cnt[t * NNODE + dp[i]], 1);
}

__global__ void scan_pass1(const int* __restrict__ cnt, int* __restrict__ bsum, int n) {
  __shared__ int red[256];
  int base = blockIdx.x * 2048;
  int s = 0;
  for (int j = 0; j < 8; j++) {
    int idx = base + j * 256 + threadIdx.x;
    s += (idx < n) ? cnt[idx] : 0;
  }
  red[threadIdx.x] = s;
  __syncthreads();
  for (int o = 128; o > 0; o >>= 1) {
    if (threadIdx.x < o) red[threadIdx.x] += red[threadIdx.x + o];
    __syncthreads();
  }
  if (threadIdx.x == 0) bsum[blockIdx.x] = red[0];
}

__global__ void scan_pass2(int* __restrict__ bsum, int nb, int* __restrict__ S, int ntot) {
  __shared__ int sh[128];
  int tid = threadIdx.x;
  int v = (tid < nb) ? bsum[tid] : 0;
  sh[tid] = v;
  __syncthreads();
  for (int o = 1; o < 128; o <<= 1) {
    int add = (tid >= o) ? sh[tid - o] : 0;
    __syncthreads();
    sh[tid] += add;
    __syncthreads();
  }
  if (tid < nb) bsum[tid] = sh[tid] - v;   // exclusive block bases
  if (tid == 0) S[ntot] = sh[127];         // grand total (= 1.6M)
}

__global__ void scan_pass3(const int* __restrict__ cnt, const int* __restrict__ bsum,
                           int* __restrict__ S, int* __restrict__ pos, int n) {
  __shared__ int sh[256];
  int tid = threadIdx.x;
  int base = blockIdx.x * 2048 + tid * 8;
  int vals[8];
  int s = 0;
  #pragma unroll
  for (int j = 0; j < 8; j++) {
    int idx = base + j;
    vals[j] = (idx < n) ? cnt[idx] : 0;
    s += vals[j];
  }
  sh[tid] = s;
  __syncthreads();
  for (int o = 1; o < 256; o <<= 1) {
    int add = (tid >= o) ? sh[tid - o] : 0;
    __syncthreads();
    sh[tid] += add;
    __syncthreads();
  }
  int run = bsum[blockIdx.x] + sh[tid] - s;  // exclusive prefix for this thread
  #pragma unroll
  for (int j = 0; j < 8; j++) {
    int idx = base + j;
    if (idx < n) { S[idx] = run; pos[idx] = run; run += vals[j]; }
  }
}

__global__ void scatter_edges(const int* __restrict__ s0, const int* __restrict__ s1,
                              const int* __restrict__ s2, const int* __restrict__ s3,
                              const int* __restrict__ d0, const int* __restrict__ d1,
                              const int* __restrict__ d2, const int* __restrict__ d3,
                              int* __restrict__ pos, int* __restrict__ srcs) {
  int t = blockIdx.y;
  const int* sp = (t == 0) ? s0 : (t == 1) ? s1 : (t == 2) ? s2 : s3;
  const int* dp = (t == 0) ? d0 : (t == 1) ? d1 : (t == 2) ? d2 : d3;
  int i = blockIdx.x * blockDim.x + threadIdx.x;
  if (i < EDGES) {
    int slot = atomicAdd(&pos[t * NNODE + dp[i]], 1);
    srcs[slot] = sp[i];
  }
}

// C = X(bf16)[M,256] @ W(f32->bf16)[256,256] + bias, out bf16.
// 64x64 block tile, 4 waves each computing a 32x32 quadrant via 16x16x32 MFMA.
#define LDW 264   // padded k-stride (shorts) for W^T in LDS; 264*2 % 16 == 0

__global__ __launch_bounds__(256) void gemm_bf16(
    const unsigned short* __restrict__ X, const float* __restrict__ W,
    const float* __restrict__ bias, unsigned short* __restrict__ out, int M)
{
  __shared__ unsigned short wt[64 * LDW];  // 33 KB
  int tid = threadIdx.x;
  int m0 = blockIdx.x * 64;
  int n0 = blockIdx.y * 64;

  // stage W^T slice [n0..n0+63][0..255] into LDS as bf16
  for (int idx = tid; idx < 64 * 256; idx += 256) {
    int n = idx & 63, k = idx >> 6;
    wt[n * LDW + k] = f2bf(W[k * 256 + n0 + n]);
  }
  __syncthreads();

  int wave = tid >> 6, lane = tid & 63;
  int wr = wave >> 1, wc = wave & 1;
  int lrow = lane & 15, kgrp = lane >> 4;
  int rowbase = m0 + 32 * wr;

  f32x4 acc[2][2];
  #pragma unroll
  for (int a = 0; a < 2; a++)
    #pragma unroll
    for (int b = 0; b < 2; b++) acc[a][b] = (f32x4){0.f, 0.f, 0.f, 0.f};

  for (int kk = 0; kk < 256; kk += 32) {
    bf16x8 af[2], bfr[2];
    #pragma unroll
    for (int mb = 0; mb < 2; mb++) {
      int r = rowbase + 16 * mb + lrow;
      if (r >= M) r = M - 1;                 // clamp; writes are guarded
      af[mb] = *reinterpret_cast<const bf16x8*>(X + (size_t)r * 256 + kk + kgrp * 8);
    }
    #pragma unroll
    for (int nb = 0; nb < 2; nb++) {
      int n = 32 * wc + 16 * nb + lrow;
      bfr[nb] = *reinterpret_cast<const bf16x8*>(&wt[n * LDW + kk + kgrp * 8]);
    }
    #pragma unroll
    for (int mb = 0; mb < 2; mb++)
      #pragma unroll
      for (int nb = 0; nb < 2; nb++)
        acc[mb][nb] = __builtin_amdgcn_mfma_f32_16x16x32_bf16(af[mb], bfr[nb], acc[mb][nb], 0, 0, 0);
  }

  // C/D layout: col = lane&15, row = (lane>>4)*4 + reg  [verified m89/m91]
  #pragma unroll
  for (int mb = 0; mb < 2; mb++) {
    #pragma unroll
    for (int nb = 0; nb < 2; nb++) {
      int col = n0 + 32 * wc + 16 * nb + lrow;
      float bv = bias[col];
      #pragma unroll
      for (int r = 0; r < 4; r++) {
        int row = rowbase + 16 * mb + kgrp * 4 + r;
        if (row < M) out[(size_t)row * 256 + col] = f2bf(acc[mb][nb][r] + bv);
      }
    }
  }
}

// One wave per dst node; fuse the two etypes feeding this ntype:
// mean per etype, sum, optional leaky_relu. MODE 0: bf16 out + relu. MODE 1: f32 out.
template<int MODE>
__global__ void agg2(const int* __restrict__ S, const int* __restrict__ srcs,
                     const unsigned short* __restrict__ whA, int etA,
                     const unsigned short* __restrict__ whB, int etB,
                     void* __restrict__ outp)
{
  int d = blockIdx.x;
  int lane = threadIdx.x;  // 64 lanes x 4 cols
  f32x4 accA = {0.f, 0.f, 0.f, 0.f}, accB = {0.f, 0.f, 0.f, 0.f};

  int gA = etA * NNODE + d;
  int a0 = S[gA], a1 = S[gA + 1];
  for (int e = a0; e < a1; e++) {
    int s = srcs[e];
    u16x4 v = *reinterpret_cast<const u16x4*>(whA + (size_t)s * DIM + lane * 4);
    accA[0] += bf2f(v[0]); accA[1] += bf2f(v[1]); accA[2] += bf2f(v[2]); accA[3] += bf2f(v[3]);
  }
  int gB = etB * NNODE + d;
  int b0 = S[gB], b1 = S[gB + 1];
  for (int e = b0; e < b1; e++) {
    int s = srcs[e];
    u16x4 v = *reinterpret_cast<const u16x4*>(whB + (size_t)s * DIM + lane * 4);
    accB[0] += bf2f(v[0]); accB[1] += bf2f(v[1]); accB[2] += bf2f(v[2]); accB[3] += bf2f(v[3]);
  }
  float ca = (float)(a1 - a0); if (ca < 1.f) ca = 1.f;
  float cb = (float)(b1 - b0); if (cb < 1.f) cb = 1.f;
  float ia = 1.f / ca, ib = 1.f / cb;
  f32x4 r;
  #pragma unroll
  for (int c = 0; c < 4; c++) r[c] = accA[c] * ia + accB[c] * ib;

  if (MODE == 0) {
    u16x4 o;
    #pragma unroll
    for (int c = 0; c < 4; c++) {
      float v = r[c];
      v = (v > 0.f) ? v : 0.01f * v;
      o[c] = f2bf(v);
    }
    reinterpret_cast<u16x4*>((unsigned short*)outp + (size_t)d * DIM)[lane] = o;
  } else {
    reinterpret_cast<f32x4*>((float*)outp + (size_t)d * DIM)[lane] = r;
  }
}

extern "C" void kernel_launch(void* const* d_in, const int* in_sizes, int n_in,
                              void* d_out, int out_size, void* d_ws, size_t ws_size,
                              hipStream_t stream) {
  (void)in_sizes; (void)n_in;
  const float* chem = (const float*)d_in[0];
  const float* gene = (const float*)d_in[1];
  const float *W1[4], *B1[4], *W2[4], *B2[4];
  const int *SRC[4], *DST[4];
  // etype order: 0=ch2ge, 1=ge2ch, 2=ch2ch, 3=ge2ge
  for (int t = 0; t < 4; t++) {
    W1[t]  = (const float*)d_in[2 + 6 * t];
    B1[t]  = (const float*)d_in[3 + 6 * t];
    W2[t]  = (const float*)d_in[4 + 6 * t];
    B2[t]  = (const float*)d_in[5 + 6 * t];
    SRC[t] = (const int*)d_in[6 + 6 * t];
    DST[t] = (const int*)d_in[7 + 6 * t];
  }

  size_t off = 0;
  auto carve = [&](size_t bytes) -> void* {
    void* p = (char*)d_ws + off;
    off += (bytes + 255) & ~(size_t)255;
    return p;
  };
  const size_t FEAT_B = (size_t)NNODE * DIM * 2;  // 25.6 MB bf16
  unsigned short* xb_chem = (unsigned short*)carve(FEAT_B);
  unsigned short* xb_gene = (unsigned short*)carve(FEAT_B);
  unsigned short* wh_a    = (unsigned short*)carve(FEAT_B);
  unsigned short* wh_b    = (unsigned short*)carve(FEAT_B);
  unsigned short* h1_chem = (unsigned short*)carve(FEAT_B);
  unsigned short* h1_gene = (unsigned short*)carve(FEAT_B);
  int* cnt  = (int*)carve((size_t)NTOT * 4);
  int* S    = (int*)carve(((size_t)NTOT + 1) * 4);
  int* pos  = (int*)carve((size_t)NTOT * 4);
  int* bsum = (int*)carve(128 * 4);
  int* srcs = (int*)carve((size_t)NET * EDGES * 4);

  if (off > ws_size) {
    // sentinel: fill output with ws_size in MB so the failure is diagnosable
    fill_f32<<<(out_size + 255) / 256, 256, 0, stream>>>((float*)d_out, (float)(ws_size >> 20), out_size);
    return;
  }

  int n4 = NNODE * DIM / 4;
  conv_f32_bf16<<<(n4 + 255) / 256, 256, 0, stream>>>(chem, xb_chem, n4);
  conv_f32_bf16<<<(n4 + 255) / 256, 256, 0, stream>>>(gene, xb_gene, n4);

  // ---- CSR build (shared by both layers) ----
  zero_i32<<<(NTOT + 255) / 256, 256, 0, stream>>>(cnt, NTOT);
  dim3 egrid((EDGES + 255) / 256, 4);
  count_edges<<<egrid, 256, 0, stream>>>(DST[0], DST[1], DST[2], DST[3], cnt);
  int nb = (NTOT + 2047) / 2048;  // 98 blocks
  scan_pass1<<<nb, 256, 0, stream>>>(cnt, bsum, NTOT);
  scan_pass2<<<1, 128, 0, stream>>>(bsum, nb, S, NTOT);
  scan_pass3<<<nb, 256, 0, stream>>>(cnt, bsum, S, pos, NTOT);
  scatter_edges<<<egrid, 256, 0, stream>>>(SRC[0], SRC[1], SRC[2], SRC[3],
                                           DST[0], DST[1], DST[2], DST[3], pos, srcs);

  dim3 ggrid((NNODE + 63) / 64, 4);
  // ---- layer 1, dt = chemical: etype 1 (ge2ch, src gene) + etype 2 (ch2ch, src chem)
  gemm_bf16<<<ggrid, 256, 0, stream>>>(xb_gene, W1[1], B1[1], wh_a, NNODE);
  gemm_bf16<<<ggrid, 256, 0, stream>>>(xb_chem, W1[2], B1[2], wh_b, NNODE);
  agg2<0><<<NNODE, 64, 0, stream>>>(S, srcs, wh_a, 1, wh_b, 2, h1_chem);
  // ---- layer 1, dt = gene: etype 0 (ch2ge, src chem) + etype 3 (ge2ge, src gene)
  gemm_bf16<<<ggrid, 256, 0, stream>>>(xb_chem, W1[0], B1[0], wh_a, NNODE);
  gemm_bf16<<<ggrid, 256, 0, stream>>>(xb_gene, W1[3], B1[3], wh_b, NNODE);
  agg2<0><<<NNODE, 64, 0, stream>>>(S, srcs, wh_a, 0, wh_b, 3, h1_gene);
  // ---- layer 2, only dt = chemical is needed for the output
  gemm_bf16<<<ggrid, 256, 0, stream>>>(h1_gene, W2[1], B2[1], wh_a, NNODE);
  gemm_bf16<<<ggrid, 256, 0, stream>>>(h1_chem, W2[2], B2[2], wh_b, NNODE);
  agg2<1><<<NNODE, 64, 0, stream>>>(S, srcs, wh_a, 1, wh_b, 2, (void*)d_out);
}